// Round 10
// baseline (55.000 us; speedup 1.0000x reference)
//
#include <hip/hip_runtime.h>
#include <stdint.h>

#define KDIM 2048
#define NEXP 64
#define MT   32              // tokens per block
#define KC   64              // k per chunk
#define NCH  (KDIM / KC)     // 32 chunks
#define NTHR 128             // 2 waves; each wave: 32 tokens x 32 experts

#define GLOBAL_AS __attribute__((address_space(1)))
#define LDS_AS    __attribute__((address_space(3)))

typedef _Float16 half8 __attribute__((ext_vector_type(8)));
typedef __fp16  fp16x2 __attribute__((ext_vector_type(2)));
typedef float f32x4 __attribute__((ext_vector_type(4)));

__device__ __forceinline__ uint32_t pkrtz(float a, float b) {
    fp16x2 h = __builtin_amdgcn_cvt_pkrtz(a, b);
    return __builtin_bit_cast(uint32_t, h);
}

struct HL { half8 h; half8 l; };

// split 8 f32 into f16 hi (exact mantissa-truncate) + f16 lo (rtz residual)
__device__ __forceinline__ HL split8(float4 a, float4 b) {
    float y[8] = {a.x, a.y, a.z, a.w, b.x, b.y, b.z, b.w};
    uint32_t hw[4], lw[4];
    #pragma unroll
    for (int i = 0; i < 4; ++i) {
        float y0 = y[2 * i], y1 = y[2 * i + 1];
        float h0 = __builtin_bit_cast(float, __builtin_bit_cast(uint32_t, y0) & 0xFFFFE000u);
        float h1 = __builtin_bit_cast(float, __builtin_bit_cast(uint32_t, y1) & 0xFFFFE000u);
        hw[i] = pkrtz(h0, h1);
        lw[i] = pkrtz(y0 - h0, y1 - h1);
    }
    HL r;
    uint4 hv = {hw[0], hw[1], hw[2], hw[3]};
    uint4 lv = {lw[0], lw[1], lw[2], lw[3]};
    r.h = __builtin_bit_cast(half8, hv);
    r.l = __builtin_bit_cast(half8, lv);
    return r;
}

// W[64][2048] f32 -> per-chunk contiguous fragment-ordered planes:
// Bf[c][pl][ks][g][lane][j] (halfs), chunk slab = 16 KB, pl-stride = 4096 halfs.
// maps to W_pl[e = g*16+(lane&15)][k = c*64 + ks*32 + (lane>>4)*8 + j]
__global__ __launch_bounds__(256) void prep_w(const float* __restrict__ W,
                                              _Float16* __restrict__ Bf) {
    int idx  = blockIdx.x * 256 + threadIdx.x;   // 16384 threads
    int lane = idx & 63;
    int g    = (idx >> 6) & 3;
    int ks   = (idx >> 8) & 1;
    int c    = idx >> 9;
    int e = g * 16 + (lane & 15);
    int k = c * 64 + ks * 32 + ((lane >> 4) << 3);
    const float4* src = reinterpret_cast<const float4*>(W + (size_t)e * KDIM + k);
    HL r = split8(src[0], src[1]);
    size_t base = (size_t)c * 8192 + ((size_t)((ks * 4 + g) * 64 + lane)) * 8;
    *reinterpret_cast<half8*>(Bf + base) = r.h;
    *reinterpret_cast<half8*>(Bf + base + 4096) = r.l;
}

__global__ __launch_bounds__(NTHR, 1) void router_kernel(const float* __restrict__ x,
                                                         const _Float16* __restrict__ Bf,
                                                         float* __restrict__ out_w,
                                                         float* __restrict__ out_i) {
    __shared__ char BsB[2][16384];   // double-buffered fragment-ordered W chunk (32 KB)

    const int tid  = threadIdx.x;
    const int lane = tid & 63;
    const int wn   = tid >> 6;           // expert half (32 exp per wave)
    const int tb   = blockIdx.x * MT;

    // A: per-lane fragment row pointers (row = lane&15 + m*16, k-base (lane>>4)*8)
    const float* xr0 = x + (size_t)(tb +      (lane & 15)) * KDIM + ((lane >> 4) << 3);
    const float* xr1 = x + (size_t)(tb + 16 + (lane & 15)) * KDIM + ((lane >> 4) << 3);

    const char* bsrc = reinterpret_cast<const char*>(Bf);

    f32x4 acc[2][2];
    #pragma unroll
    for (int m = 0; m < 2; ++m)
        #pragma unroll
        for (int n = 0; n < 2; ++n)
            acc[m][n] = (f32x4){0.f, 0.f, 0.f, 0.f};

    float4 As0[8], As1[8];   // two named A-sets; all indices compile-time

    auto ISSUE = [&](int buf, float4* AS, int c) {
        // B: linear DMA of the 16 KB fragment-ordered slab (no VGPR, no ds_write)
        #pragma unroll
        for (int i = 0; i < 8; ++i) {
            int off = tid * 16 + i * 2048;
            __builtin_amdgcn_global_load_lds(
                (const GLOBAL_AS uint32_t*)(bsrc + (size_t)c * 16384 + off),
                (LDS_AS uint32_t*)(&BsB[buf][0] + off),
                16, 0, 0);
        }
        // A: direct per-lane fragment loads [m][ks][half]
        #pragma unroll
        for (int m = 0; m < 2; ++m) {
            const float* base = (m ? xr1 : xr0) + c * KC;
            #pragma unroll
            for (int ks = 0; ks < 2; ++ks)
                #pragma unroll
                for (int h = 0; h < 2; ++h)
                    AS[(m * 2 + ks) * 2 + h] =
                        *reinterpret_cast<const float4*>(base + ks * 32 + h * 4);
        }
    };

    auto COMP = [&](int buf, const float4* AS) {
        half8 bh[2][2], bl[2][2];   // [ks][n]
        #pragma unroll
        for (int ks = 0; ks < 2; ++ks)
            #pragma unroll
            for (int n = 0; n < 2; ++n) {
                int off = ((ks * 4 + wn * 2 + n) * 64 + lane) * 16;
                bh[ks][n] = *reinterpret_cast<const half8*>(&BsB[buf][off]);
                bl[ks][n] = *reinterpret_cast<const half8*>(&BsB[buf][off + 8192]);
            }
        #pragma unroll
        for (int m = 0; m < 2; ++m)
            #pragma unroll
            for (int ks = 0; ks < 2; ++ks) {
                HL a = split8(AS[(m * 2 + ks) * 2 + 0], AS[(m * 2 + ks) * 2 + 1]);
                #pragma unroll
                for (int n = 0; n < 2; ++n) {
                    acc[m][n] = __builtin_amdgcn_mfma_f32_16x16x32_f16(a.h, bh[ks][n], acc[m][n], 0, 0, 0);
                    acc[m][n] = __builtin_amdgcn_mfma_f32_16x16x32_f16(a.l, bh[ks][n], acc[m][n], 0, 0, 0);
                    acc[m][n] = __builtin_amdgcn_mfma_f32_16x16x32_f16(a.h, bl[ks][n], acc[m][n], 0, 0, 0);
                }
            }
    };

    // prologue: chunk 0 in flight
    ISSUE(0, As0, 0);

    // main: __syncthreads drains exactly the ops we need (gll(c)+A(c), issued a
    // full compute-phase earlier); the CU's other block hides the residual.
    for (int q = 0; q < 15; ++q) {
        __syncthreads();
        ISSUE(1, As1, 2 * q + 1);
        COMP(0, As0);
        __syncthreads();
        ISSUE(0, As0, 2 * q + 2);
        COMP(1, As1);
    }
    __syncthreads();
    ISSUE(1, As1, 31);
    COMP(0, As0);            // c = 30
    __syncthreads();
    COMP(1, As1);            // c = 31

    // ---- epilogue: top-2 per token (score buffer overlaid on BsB) ----
    __syncthreads();
    float (*ss)[NEXP + 3] = reinterpret_cast<float (*)[NEXP + 3]>(&BsB[0][0]);  // 8.6 KB
    #pragma unroll
    for (int m = 0; m < 2; ++m)
        #pragma unroll
        for (int n = 0; n < 2; ++n)
            #pragma unroll
            for (int r = 0; r < 4; ++r) {
                int tok = m * 16 + (lane >> 4) * 4 + r;       // C/D: row=(lane>>4)*4+reg
                int e   = wn * 32 + n * 16 + (lane & 15);     //      col=lane&15 (m89)
                ss[tok][e] = acc[m][n][r];
            }
    __syncthreads();

    if (tid < MT) {
        const int t = tid;
        float m1 = -1e30f, m2 = -1e30f;
        int i1 = 0, i2 = 0;
        // strict '>' keeps the lower index on ties, matching jax.lax.top_k
        #pragma unroll
        for (int e = 0; e < NEXP; ++e) {
            float v = ss[t][e];
            if (v > m1) { m2 = m1; i2 = i1; m1 = v; i1 = e; }
            else if (v > m2) { m2 = v; i2 = e; }
        }
        const int gt = tb + t;
        out_w[gt * 2 + 0] = m1;
        out_w[gt * 2 + 1] = m2;
        out_i[gt * 2 + 0] = (float)i1;
        out_i[gt * 2 + 1] = (float)i2;
    }
}

extern "C" void kernel_launch(void* const* d_in, const int* in_sizes, int n_in,
                              void* d_out, int out_size, void* d_ws, size_t ws_size,
                              hipStream_t stream) {
    const float* x = (const float*)d_in[0];   // [16384, 2048] f32
    const float* W = (const float*)d_in[1];   // [64, 2048]   f32
    float* out = (float*)d_out;               // [16384*2 weights][16384*2 indices]

    const int n_tokens = in_sizes[0] / KDIM;  // 16384
    _Float16* Bfp = (_Float16*)d_ws;          // 512 KB fragment-ordered W (h+l planes)

    hipLaunchKernelGGL(prep_w, dim3(64), dim3(256), 0, stream, W, Bfp);
    hipLaunchKernelGGL(router_kernel, dim3(n_tokens / MT), dim3(NTHR), 0, stream,
                       x, Bfp, out, out + 2 * (size_t)n_tokens);
}